// Round 1
// 345.509 us; speedup vs baseline: 1.1534x; 1.1534x over previous
//
#include <hip/hip_runtime.h>
#include <hip/hip_bf16.h>

typedef __hip_bfloat16 bf16;
typedef __attribute__((ext_vector_type(8))) short short8;
typedef __attribute__((ext_vector_type(16))) float floatx16;

#define NB 4
#define NC 512
#define CQ 64
#define NN 4096
#define MFMA32 __builtin_amdgcn_mfma_f32_32x32x16_bf16

#define PQ 72   // qlds pitch (bf16): 144B rows, 16B aligned
#define PM 264  // plds pitch (bf16): 528B rows, 16B aligned
#define PA 40   // proj W-tile pitch
#define PB 40   // proj X-tile pitch

// ---------------------------------------------------------------------------
// Merged q/k/v 1x1-conv GEMM: C[co][n] = W[co][c] * X[c][n] + bias.
// Tile 64co x 256n, BK=32. fp32 global -> bf16 LDS staging.
//   mt==0 : W=Wq, X=x,    write qt transposed [b][n][64]
//   mt==1 : W=Wk, X=skel, write kt transposed [b][n][64]
//   mt>=2 : W=Wv rows (mt-2)*64.., X=skel, write vf [b][co][n]
// grid: (16 n-tiles, 10 m-tiles, NB), block 256.
// ---------------------------------------------------------------------------
__global__ __launch_bounds__(256) void proj_all(
    const float* __restrict__ x, const float* __restrict__ skel,
    const float* __restrict__ Wq, const float* __restrict__ bq,
    const float* __restrict__ Wk, const float* __restrict__ bk,
    const float* __restrict__ Wv, const float* __restrict__ bv,
    bf16* __restrict__ qt, bf16* __restrict__ ktO, bf16* __restrict__ vf) {
  __shared__ bf16 At[64 * PA];
  __shared__ bf16 Bt[256 * PB];
  int tid = threadIdx.x, lane = tid & 63, wave = tid >> 6;
  int col = lane & 31, half = lane >> 5;
  int nt = blockIdx.x, mt = blockIdx.y, b = blockIdx.z;
  int nbase = nt * 256;
  const float* Wp = (mt == 0) ? Wq
                  : (mt == 1) ? Wk
                              : Wv + (size_t)(mt - 2) * 64 * NC;
  const float* Xb = ((mt == 0) ? x : skel) + (size_t)b * NC * NN;

  floatx16 acc[2][2];
#pragma unroll
  for (int i = 0; i < 2; ++i)
#pragma unroll
    for (int j = 0; j < 2; ++j) acc[i][j] = (floatx16)(0.f);

  int wr = tid >> 2, wch = tid & 3;         // W staging: row, 8-wide k-chunk
  int xg = tid & 63, xc0 = (tid >> 6) * 8;  // X staging: n-group of 4, c-base

  for (int k0 = 0; k0 < NC; k0 += 32) {
    {  // stage W tile -> At[64][32]
      const float* wp = Wp + (size_t)wr * NC + k0 + wch * 8;
      float4 f0 = *(const float4*)(wp);
      float4 f1 = *(const float4*)(wp + 4);
      bf16 t8[8] = {__float2bfloat16(f0.x), __float2bfloat16(f0.y),
                    __float2bfloat16(f0.z), __float2bfloat16(f0.w),
                    __float2bfloat16(f1.x), __float2bfloat16(f1.y),
                    __float2bfloat16(f1.z), __float2bfloat16(f1.w)};
      *(uint4*)(At + wr * PA + wch * 8) = *(const uint4*)t8;
    }
    {  // stage X tile -> Bt[256][32] (transposed: [n][k])
      float xs[8][4];
#pragma unroll
      for (int cc = 0; cc < 8; ++cc) {
        float4 f = *(const float4*)(Xb + (size_t)(k0 + xc0 + cc) * NN + nbase + xg * 4);
        xs[cc][0] = f.x; xs[cc][1] = f.y; xs[cc][2] = f.z; xs[cc][3] = f.w;
      }
#pragma unroll
      for (int nn = 0; nn < 4; ++nn) {
        bf16 t8[8];
#pragma unroll
        for (int cc = 0; cc < 8; ++cc) t8[cc] = __float2bfloat16(xs[cc][nn]);
        *(uint4*)(Bt + (xg * 4 + nn) * PB + xc0) = *(const uint4*)t8;
      }
    }
    __syncthreads();
#pragma unroll
    for (int ks = 0; ks < 2; ++ks) {
      short8 a0 = *(const short8*)(At + col * PA + ks * 16 + half * 8);
      short8 a1 = *(const short8*)(At + (col + 32) * PA + ks * 16 + half * 8);
      short8 q0 = *(const short8*)(Bt + (wave * 64 + col) * PB + ks * 16 + half * 8);
      short8 q1 = *(const short8*)(Bt + (wave * 64 + 32 + col) * PB + ks * 16 + half * 8);
      acc[0][0] = MFMA32(a0, q0, acc[0][0], 0, 0, 0);
      acc[0][1] = MFMA32(a0, q1, acc[0][1], 0, 0, 0);
      acc[1][0] = MFMA32(a1, q0, acc[1][0], 0, 0, 0);
      acc[1][1] = MFMA32(a1, q1, acc[1][1], 0, 0, 0);
    }
    __syncthreads();
  }
  // epilogue: C/D layout col=lane&31 -> n, row=(r&3)+8*(r>>2)+4*half -> co
#pragma unroll
  for (int ms = 0; ms < 2; ++ms)
#pragma unroll
    for (int r = 0; r < 16; ++r) {
      int co = ms * 32 + (r & 3) + 8 * (r >> 2) + 4 * half;
      float bb = (mt == 0) ? bq[co] : (mt == 1) ? bk[co] : bv[(mt - 2) * 64 + co];
#pragma unroll
      for (int ns = 0; ns < 2; ++ns) {
        int n = nbase + wave * 64 + ns * 32 + col;
        float v = acc[ms][ns][r] + bb;
        if (mt == 0)
          qt[((size_t)b * NN + n) * CQ + co] = __float2bfloat16(v);
        else if (mt == 1)
          ktO[((size_t)b * NN + n) * CQ + co] = __float2bfloat16(v);
        else
          vf[((size_t)b * NC + (mt - 2) * 64 + co) * NN + n] = __float2bfloat16(v);
      }
    }
}

// ---------------------------------------------------------------------------
// Cooperative MFMA flash attention. Block = (batch, 64 queries), 8 waves
// (512 threads -> 2 waves/SIMD for latency hiding; same per-block V traffic
// as 4 waves). Per 256-m chunk: wave w computes S^T for its 32-m subtile
// (8 MFMA), softmax max/sum shared via LDS (2 barriers/chunk), P tile in
// LDS, then each wave does PV for its 64 channels (64 MFMA).
// XCD-aware grid: batch b pinned to XCD pair {2b,2b+1} so V[b] (4MB) stays
// resident in that XCD's 4MB L2 instead of thrashing 16MB across every L2.
// grid: 256 (1D), block 512.
// ---------------------------------------------------------------------------
__global__ __launch_bounds__(512, 2) void attn_flash(
    const bf16* __restrict__ qt, const bf16* __restrict__ kt,
    const bf16* __restrict__ vf, const float* __restrict__ x,
    const float* __restrict__ gamma, float* __restrict__ out0) {
  __shared__ bf16 qlds[64 * PQ];
  __shared__ bf16 plds[64 * PM];
  __shared__ float lred[8][2][32];
  __shared__ float sred[8][2][32];
  int tid = threadIdx.x, lane = tid & 63, wave = tid >> 6;
  int col = lane & 31, half = lane >> 5;
  // XCD-aware mapping (round-robin dispatch: XCD = bid % 8)
  int lid = blockIdx.x;
  int xcd = lid & 7;
  int b = xcd >> 1;
  int n0 = ((lid >> 3) * 2 + (xcd & 1)) * 64;
  const float L2E = 1.44269504f;

  // stage Q tile [64 n][64 cq]: 512 threads x one uint4
  {
    int r = tid >> 3, ch = tid & 7;
    *(uint4*)(qlds + r * PQ + ch * 8) =
        *(const uint4*)(qt + ((size_t)b * NN + n0 + r) * CQ + ch * 8);
  }
  __syncthreads();

  floatx16 acc[2][2];
#pragma unroll
  for (int t = 0; t < 2; ++t)
#pragma unroll
    for (int ns = 0; ns < 2; ++ns) acc[t][ns] = (floatx16)(0.f);
  float run_max[2] = {-3.0e38f, -3.0e38f}, run_sum[2] = {0.f, 0.f};

  const bf16* kb = kt + (size_t)b * NN * CQ;
  const bf16* vb = vf + (size_t)b * NC * NN + (size_t)(wave * 64 + col) * NN;

  for (int it = 0; it < 16; ++it) {
    int m0 = it * 256;
    int mw = m0 + wave * 32;
    // ---- S^T for this wave's 32-m subtile: D[m][n], n on lanes ----------
    floatx16 s[2];
#pragma unroll
    for (int ns = 0; ns < 2; ++ns) s[ns] = (floatx16)(0.f);
    const bf16* kp = kb + (size_t)(mw + col) * CQ + half * 8;
#pragma unroll
    for (int ks = 0; ks < 4; ++ks) {
      short8 a0 = *(const short8*)(kp + ks * 16);
      short8 q0 = *(const short8*)(qlds + col * PQ + ks * 16 + half * 8);
      short8 q1 = *(const short8*)(qlds + (32 + col) * PQ + ks * 16 + half * 8);
      s[0] = MFMA32(a0, q0, s[0], 0, 0, 0);
      s[1] = MFMA32(a0, q1, s[1], 0, 0, 0);
    }
    // ---- wave-local max over its 32 m, publish ---------------------------
#pragma unroll
    for (int ns = 0; ns < 2; ++ns) {
      float lm = s[ns][0];
#pragma unroll
      for (int r = 1; r < 16; ++r) lm = fmaxf(lm, s[ns][r]);
      lm = fmaxf(lm, __shfl_xor(lm, 32));
      if (half == 0) lred[wave][ns][col] = lm;
    }
    __syncthreads();  // A: lmax visible; also orders prev-iter PV before P-write
    float nm[2], alpha[2];
#pragma unroll
    for (int ns = 0; ns < 2; ++ns) {
      float m8 = lred[0][ns][col];
#pragma unroll
      for (int w = 1; w < 8; ++w) m8 = fmaxf(m8, lred[w][ns][col]);
      nm[ns] = fmaxf(run_max[ns], m8);
      alpha[ns] = exp2f((run_max[ns] - nm[ns]) * L2E);
      run_max[ns] = nm[ns];
    }
    // ---- P = exp(S - nm), write LDS [n][m-chunk 256], partial sums -------
    float psum[2] = {0.f, 0.f};
#pragma unroll
    for (int ns = 0; ns < 2; ++ns) {
      float pv[16];
#pragma unroll
      for (int r = 0; r < 16; ++r) {
        pv[r] = exp2f((s[ns][r] - nm[ns]) * L2E);
        psum[ns] += pv[r];
      }
      bf16* pw = plds + (ns * 32 + col) * PM + wave * 32 + 4 * half;
#pragma unroll
      for (int rg = 0; rg < 4; ++rg) {  // m = .. + rg*8 + {0,1,2,3}
        bf16 t4[4] = {__float2bfloat16(pv[4 * rg]), __float2bfloat16(pv[4 * rg + 1]),
                      __float2bfloat16(pv[4 * rg + 2]), __float2bfloat16(pv[4 * rg + 3])};
        *(uint2*)(pw + rg * 8) = *(const uint2*)t4;
      }
    }
#pragma unroll
    for (int ns = 0; ns < 2; ++ns) {
      float ps = psum[ns] + __shfl_xor(psum[ns], 32);
      if (half == 0) sred[wave][ns][col] = ps;
    }
    if (__any((alpha[0] < 1.f) || (alpha[1] < 1.f))) {
#pragma unroll
      for (int t = 0; t < 2; ++t)
#pragma unroll
        for (int ns = 0; ns < 2; ++ns)
#pragma unroll
          for (int r = 0; r < 16; ++r) acc[t][ns][r] *= alpha[ns];
    }
    __syncthreads();  // B: P + psums visible
#pragma unroll
    for (int ns = 0; ns < 2; ++ns) {
      float ss = sred[0][ns][col];
#pragma unroll
      for (int w = 1; w < 8; ++w) ss += sred[w][ns][col];
      run_sum[ns] = run_sum[ns] * alpha[ns] + ss;
    }
    // ---- PV over full 256-m chunk: D[c][n] += V[c][m] P^T[m][n] ----------
    const bf16* vp = vb + m0 + half * 8;
#pragma unroll 4
    for (int ki = 0; ki < 16; ++ki) {
      short8 p0 = *(const short8*)(plds + col * PM + ki * 16 + half * 8);
      short8 p1 = *(const short8*)(plds + (32 + col) * PM + ki * 16 + half * 8);
#pragma unroll
      for (int t = 0; t < 2; ++t) {
        short8 av = *(const short8*)(vp + (size_t)t * 32 * NN + ki * 16);
        acc[t][0] = MFMA32(av, p0, acc[t][0], 0, 0, 0);
        acc[t][1] = MFMA32(av, p1, acc[t][1], 0, 0, 0);
      }
    }
  }
  // ---- epilogue: out0 = gamma/denom * acc + x ----------------------------
  float g = gamma[0];
  float scl[2] = {g / run_sum[0], g / run_sum[1]};
#pragma unroll
  for (int t = 0; t < 2; ++t)
#pragma unroll
    for (int r = 0; r < 16; ++r) {
      int c = wave * 64 + t * 32 + (r & 3) + 8 * (r >> 2) + 4 * half;
      size_t rowb = (size_t)b * NC * NN + (size_t)c * NN + n0 + col;
#pragma unroll
      for (int ns = 0; ns < 2; ++ns) {
        size_t idx = rowb + ns * 32;
        out0[idx] = scl[ns] * acc[t][ns][r] + x[idx];
      }
    }
}

// ---------------------------------------------------------------------------
// out1 = x flattened (exact fp32 copy), 4 elements / thread.
// ---------------------------------------------------------------------------
__global__ __launch_bounds__(256) void copy_x(const float* __restrict__ x,
                                              float* __restrict__ out1) {
  size_t i = ((size_t)blockIdx.x * 256 + threadIdx.x) * 4;
  *reinterpret_cast<float4*>(out1 + i) =
      *reinterpret_cast<const float4*>(x + i);
}

extern "C" void kernel_launch(void* const* d_in, const int* in_sizes, int n_in,
                              void* d_out, int out_size, void* d_ws,
                              size_t ws_size, hipStream_t stream) {
  const float* x     = (const float*)d_in[0];
  // d_in[1] = style (unused by the reference)
  const float* skel  = (const float*)d_in[2];
  const float* Wq    = (const float*)d_in[3];
  const float* bq    = (const float*)d_in[4];
  const float* Wk    = (const float*)d_in[5];
  const float* bk    = (const float*)d_in[6];
  const float* Wv    = (const float*)d_in[7];
  const float* bv    = (const float*)d_in[8];
  const float* gamma = (const float*)d_in[9];

  // ws (4 MB): qt [B][N][64] bf16 + kt [B][N][64] bf16.
  // vf [B][C][N] bf16 (16.8 MB) lives in the out1 half of d_out; attn reads
  // vf / writes out0 only; copy_x overwrites out1 afterwards (stream order).
  bf16* qt = (bf16*)d_ws;
  bf16* kt = qt + (size_t)NB * NN * CQ;

  float* out0 = (float*)d_out;
  float* out1 = out0 + (size_t)NB * NC * NN;
  bf16*  vf   = (bf16*)out1;  // scratch until copy_x runs

  // merged q (mt0, from x) + k (mt1, from skel) + v (mt2..9, from skel)
  proj_all<<<dim3(16, 10, NB), dim3(256), 0, stream>>>(
      x, skel, Wq, bq, Wk, bk, Wv, bv, qt, kt, vf);
  attn_flash<<<dim3(256), dim3(512), 0, stream>>>(qt, kt, vf, x, gamma, out0);
  copy_x<<<dim3(8192), dim3(256), 0, stream>>>(x, out1);
}

// Round 2
// 340.044 us; speedup vs baseline: 1.1720x; 1.0161x over previous
//
#include <hip/hip_runtime.h>
#include <hip/hip_bf16.h>

typedef __hip_bfloat16 bf16;
typedef __attribute__((ext_vector_type(8))) short short8;
typedef __attribute__((ext_vector_type(16))) float floatx16;

#define NB 4
#define NC 512
#define CQ 64
#define NN 4096
#define PVN 4224  // vf row pitch (elements): 8448B rows — breaks 8KB power-of-2
                  // stride so PV's 32-row gather spreads across all L2 slices
#define MFMA32 __builtin_amdgcn_mfma_f32_32x32x16_bf16

#define PQ 72   // qlds pitch (bf16): 144B rows, 16B aligned
#define PM 264  // plds pitch (bf16): 528B rows, 16B aligned
#define PA 40   // proj W-tile pitch
#define PB 40   // proj X-tile pitch

// ---------------------------------------------------------------------------
// Merged q/k/v 1x1-conv GEMM: C[co][n] = W[co][c] * X[c][n] + bias.
// Tile 64co x 256n, BK=32. fp32 global -> bf16 LDS staging.
//   mt==0 : W=Wq, X=x,    write qt transposed [b][n][64]
//   mt==1 : W=Wk, X=skel, write kt transposed [b][n][64]
//   mt>=2 : W=Wv rows (mt-2)*64.., X=skel, write vf [b][co][PVN-pitched n]
// grid: (16 n-tiles, 10 m-tiles, NB), block 256.
// ---------------------------------------------------------------------------
__global__ __launch_bounds__(256) void proj_all(
    const float* __restrict__ x, const float* __restrict__ skel,
    const float* __restrict__ Wq, const float* __restrict__ bq,
    const float* __restrict__ Wk, const float* __restrict__ bk,
    const float* __restrict__ Wv, const float* __restrict__ bv,
    bf16* __restrict__ qt, bf16* __restrict__ ktO, bf16* __restrict__ vf) {
  __shared__ bf16 At[64 * PA];
  __shared__ bf16 Bt[256 * PB];
  int tid = threadIdx.x, lane = tid & 63, wave = tid >> 6;
  int col = lane & 31, half = lane >> 5;
  int nt = blockIdx.x, mt = blockIdx.y, b = blockIdx.z;
  int nbase = nt * 256;
  const float* Wp = (mt == 0) ? Wq
                  : (mt == 1) ? Wk
                              : Wv + (size_t)(mt - 2) * 64 * NC;
  const float* Xb = ((mt == 0) ? x : skel) + (size_t)b * NC * NN;

  floatx16 acc[2][2];
#pragma unroll
  for (int i = 0; i < 2; ++i)
#pragma unroll
    for (int j = 0; j < 2; ++j) acc[i][j] = (floatx16)(0.f);

  int wr = tid >> 2, wch = tid & 3;         // W staging: row, 8-wide k-chunk
  int xg = tid & 63, xc0 = (tid >> 6) * 8;  // X staging: n-group of 4, c-base

  for (int k0 = 0; k0 < NC; k0 += 32) {
    {  // stage W tile -> At[64][32]
      const float* wp = Wp + (size_t)wr * NC + k0 + wch * 8;
      float4 f0 = *(const float4*)(wp);
      float4 f1 = *(const float4*)(wp + 4);
      bf16 t8[8] = {__float2bfloat16(f0.x), __float2bfloat16(f0.y),
                    __float2bfloat16(f0.z), __float2bfloat16(f0.w),
                    __float2bfloat16(f1.x), __float2bfloat16(f1.y),
                    __float2bfloat16(f1.z), __float2bfloat16(f1.w)};
      *(uint4*)(At + wr * PA + wch * 8) = *(const uint4*)t8;
    }
    {  // stage X tile -> Bt[256][32] (transposed: [n][k])
      float xs[8][4];
#pragma unroll
      for (int cc = 0; cc < 8; ++cc) {
        float4 f = *(const float4*)(Xb + (size_t)(k0 + xc0 + cc) * NN + nbase + xg * 4);
        xs[cc][0] = f.x; xs[cc][1] = f.y; xs[cc][2] = f.z; xs[cc][3] = f.w;
      }
#pragma unroll
      for (int nn = 0; nn < 4; ++nn) {
        bf16 t8[8];
#pragma unroll
        for (int cc = 0; cc < 8; ++cc) t8[cc] = __float2bfloat16(xs[cc][nn]);
        *(uint4*)(Bt + (xg * 4 + nn) * PB + xc0) = *(const uint4*)t8;
      }
    }
    __syncthreads();
#pragma unroll
    for (int ks = 0; ks < 2; ++ks) {
      short8 a0 = *(const short8*)(At + col * PA + ks * 16 + half * 8);
      short8 a1 = *(const short8*)(At + (col + 32) * PA + ks * 16 + half * 8);
      short8 q0 = *(const short8*)(Bt + (wave * 64 + col) * PB + ks * 16 + half * 8);
      short8 q1 = *(const short8*)(Bt + (wave * 64 + 32 + col) * PB + ks * 16 + half * 8);
      acc[0][0] = MFMA32(a0, q0, acc[0][0], 0, 0, 0);
      acc[0][1] = MFMA32(a0, q1, acc[0][1], 0, 0, 0);
      acc[1][0] = MFMA32(a1, q0, acc[1][0], 0, 0, 0);
      acc[1][1] = MFMA32(a1, q1, acc[1][1], 0, 0, 0);
    }
    __syncthreads();
  }
  // epilogue: C/D layout col=lane&31 -> n, row=(r&3)+8*(r>>2)+4*half -> co
#pragma unroll
  for (int ms = 0; ms < 2; ++ms)
#pragma unroll
    for (int r = 0; r < 16; ++r) {
      int co = ms * 32 + (r & 3) + 8 * (r >> 2) + 4 * half;
      float bb = (mt == 0) ? bq[co] : (mt == 1) ? bk[co] : bv[(mt - 2) * 64 + co];
#pragma unroll
      for (int ns = 0; ns < 2; ++ns) {
        int n = nbase + wave * 64 + ns * 32 + col;
        float v = acc[ms][ns][r] + bb;
        if (mt == 0)
          qt[((size_t)b * NN + n) * CQ + co] = __float2bfloat16(v);
        else if (mt == 1)
          ktO[((size_t)b * NN + n) * CQ + co] = __float2bfloat16(v);
        else
          vf[((size_t)b * NC + (mt - 2) * 64 + co) * PVN + n] = __float2bfloat16(v);
      }
    }
}

// ---------------------------------------------------------------------------
// Cooperative MFMA flash attention. Block = (batch, 64 queries), 8 waves
// (512 threads, 2 waves/SIMD). Per 256-m chunk: wave w computes S^T for its
// 32-m subtile (8 MFMA), softmax max/sum shared via LDS (2 barriers/chunk),
// P tile in LDS, then each wave does PV for its 64 channels (64 MFMA).
// XCD-aware grid: batch b pinned to XCD pair {2b,2b+1} so V[b] stays L2
// resident. V rows PVN-pitched (8448B) to spread the PV gather over all L2
// slices instead of serializing on one (8KB power-of-2 stride pathology).
// grid: 256 (1D), block 512.
// ---------------------------------------------------------------------------
__global__ __launch_bounds__(512, 2) void attn_flash(
    const bf16* __restrict__ qt, const bf16* __restrict__ kt,
    const bf16* __restrict__ vf, const float* __restrict__ x,
    const float* __restrict__ gamma, float* __restrict__ out0) {
  __shared__ bf16 qlds[64 * PQ];
  __shared__ bf16 plds[64 * PM];
  __shared__ float lred[8][2][32];
  __shared__ float sred[8][2][32];
  int tid = threadIdx.x, lane = tid & 63, wave = tid >> 6;
  int col = lane & 31, half = lane >> 5;
  // XCD-aware mapping (round-robin dispatch: XCD = bid % 8)
  int lid = blockIdx.x;
  int xcd = lid & 7;
  int b = xcd >> 1;
  int n0 = ((lid >> 3) * 2 + (xcd & 1)) * 64;
  const float L2E = 1.44269504f;

  // stage Q tile [64 n][64 cq]: 512 threads x one uint4
  {
    int r = tid >> 3, ch = tid & 7;
    *(uint4*)(qlds + r * PQ + ch * 8) =
        *(const uint4*)(qt + ((size_t)b * NN + n0 + r) * CQ + ch * 8);
  }
  __syncthreads();

  floatx16 acc[2][2];
#pragma unroll
  for (int t = 0; t < 2; ++t)
#pragma unroll
    for (int ns = 0; ns < 2; ++ns) acc[t][ns] = (floatx16)(0.f);
  float run_max[2] = {-3.0e38f, -3.0e38f}, run_sum[2] = {0.f, 0.f};

  const bf16* kb = kt + (size_t)b * NN * CQ;
  const bf16* vb = vf + (size_t)b * NC * PVN + (size_t)(wave * 64 + col) * PVN;

  for (int it = 0; it < 16; ++it) {
    int m0 = it * 256;
    int mw = m0 + wave * 32;
    // ---- S^T for this wave's 32-m subtile: D[m][n], n on lanes ----------
    floatx16 s[2];
#pragma unroll
    for (int ns = 0; ns < 2; ++ns) s[ns] = (floatx16)(0.f);
    const bf16* kp = kb + (size_t)(mw + col) * CQ + half * 8;
#pragma unroll
    for (int ks = 0; ks < 4; ++ks) {
      short8 a0 = *(const short8*)(kp + ks * 16);
      short8 q0 = *(const short8*)(qlds + col * PQ + ks * 16 + half * 8);
      short8 q1 = *(const short8*)(qlds + (32 + col) * PQ + ks * 16 + half * 8);
      s[0] = MFMA32(a0, q0, s[0], 0, 0, 0);
      s[1] = MFMA32(a0, q1, s[1], 0, 0, 0);
    }
    // ---- wave-local max over its 32 m, publish ---------------------------
#pragma unroll
    for (int ns = 0; ns < 2; ++ns) {
      float lm = s[ns][0];
#pragma unroll
      for (int r = 1; r < 16; ++r) lm = fmaxf(lm, s[ns][r]);
      lm = fmaxf(lm, __shfl_xor(lm, 32));
      if (half == 0) lred[wave][ns][col] = lm;
    }
    __syncthreads();  // A: lmax visible; also orders prev-iter PV before P-write
    float nm[2], alpha[2];
#pragma unroll
    for (int ns = 0; ns < 2; ++ns) {
      float m8 = lred[0][ns][col];
#pragma unroll
      for (int w = 1; w < 8; ++w) m8 = fmaxf(m8, lred[w][ns][col]);
      nm[ns] = fmaxf(run_max[ns], m8);
      alpha[ns] = exp2f((run_max[ns] - nm[ns]) * L2E);
      run_max[ns] = nm[ns];
    }
    // ---- P = exp(S - nm), write LDS [n][m-chunk 256], partial sums -------
    float psum[2] = {0.f, 0.f};
#pragma unroll
    for (int ns = 0; ns < 2; ++ns) {
      float pv[16];
#pragma unroll
      for (int r = 0; r < 16; ++r) {
        pv[r] = exp2f((s[ns][r] - nm[ns]) * L2E);
        psum[ns] += pv[r];
      }
      bf16* pw = plds + (ns * 32 + col) * PM + wave * 32 + 4 * half;
#pragma unroll
      for (int rg = 0; rg < 4; ++rg) {  // m = .. + rg*8 + {0,1,2,3}
        bf16 t4[4] = {__float2bfloat16(pv[4 * rg]), __float2bfloat16(pv[4 * rg + 1]),
                      __float2bfloat16(pv[4 * rg + 2]), __float2bfloat16(pv[4 * rg + 3])};
        *(uint2*)(pw + rg * 8) = *(const uint2*)t4;
      }
    }
#pragma unroll
    for (int ns = 0; ns < 2; ++ns) {
      float ps = psum[ns] + __shfl_xor(psum[ns], 32);
      if (half == 0) sred[wave][ns][col] = ps;
    }
    if (__any((alpha[0] < 1.f) || (alpha[1] < 1.f))) {
#pragma unroll
      for (int t = 0; t < 2; ++t)
#pragma unroll
        for (int ns = 0; ns < 2; ++ns)
#pragma unroll
          for (int r = 0; r < 16; ++r) acc[t][ns][r] *= alpha[ns];
    }
    __syncthreads();  // B: P + psums visible
#pragma unroll
    for (int ns = 0; ns < 2; ++ns) {
      float ss = sred[0][ns][col];
#pragma unroll
      for (int w = 1; w < 8; ++w) ss += sred[w][ns][col];
      run_sum[ns] = run_sum[ns] * alpha[ns] + ss;
    }
    // ---- PV over full 256-m chunk: D[c][n] += V[c][m] P^T[m][n] ----------
    const bf16* vp = vb + m0 + half * 8;
#pragma unroll 4
    for (int ki = 0; ki < 16; ++ki) {
      short8 p0 = *(const short8*)(plds + col * PM + ki * 16 + half * 8);
      short8 p1 = *(const short8*)(plds + (32 + col) * PM + ki * 16 + half * 8);
#pragma unroll
      for (int t = 0; t < 2; ++t) {
        short8 av = *(const short8*)(vp + (size_t)t * 32 * PVN + ki * 16);
        acc[t][0] = MFMA32(av, p0, acc[t][0], 0, 0, 0);
        acc[t][1] = MFMA32(av, p1, acc[t][1], 0, 0, 0);
      }
    }
  }
  // ---- epilogue: out0 = gamma/denom * acc + x ----------------------------
  float g = gamma[0];
  float scl[2] = {g / run_sum[0], g / run_sum[1]};
#pragma unroll
  for (int t = 0; t < 2; ++t)
#pragma unroll
    for (int r = 0; r < 16; ++r) {
      int c = wave * 64 + t * 32 + (r & 3) + 8 * (r >> 2) + 4 * half;
      size_t rowb = (size_t)b * NC * NN + (size_t)c * NN + n0 + col;
#pragma unroll
      for (int ns = 0; ns < 2; ++ns) {
        size_t idx = rowb + ns * 32;
        out0[idx] = scl[ns] * acc[t][ns][r] + x[idx];
      }
    }
}

// ---------------------------------------------------------------------------
// out1 = x flattened (exact fp32 copy), 4 elements / thread.
// ---------------------------------------------------------------------------
__global__ __launch_bounds__(256) void copy_x(const float* __restrict__ x,
                                              float* __restrict__ out1) {
  size_t i = ((size_t)blockIdx.x * 256 + threadIdx.x) * 4;
  *reinterpret_cast<float4*>(out1 + i) =
      *reinterpret_cast<const float4*>(x + i);
}

extern "C" void kernel_launch(void* const* d_in, const int* in_sizes, int n_in,
                              void* d_out, int out_size, void* d_ws,
                              size_t ws_size, hipStream_t stream) {
  const float* x     = (const float*)d_in[0];
  // d_in[1] = style (unused by the reference)
  const float* skel  = (const float*)d_in[2];
  const float* Wq    = (const float*)d_in[3];
  const float* bq    = (const float*)d_in[4];
  const float* Wk    = (const float*)d_in[5];
  const float* bk    = (const float*)d_in[6];
  const float* Wv    = (const float*)d_in[7];
  const float* bv    = (const float*)d_in[8];
  const float* gamma = (const float*)d_in[9];

  // ws (4 MB): qt [B][N][64] bf16 + kt [B][N][64] bf16.
  // vf [B][C][PVN] bf16 (17.3 MB, padded pitch) lives in the out1 half of
  // d_out; attn reads vf / writes out0 only; copy_x overwrites out1 after.
  bf16* qt = (bf16*)d_ws;
  bf16* kt = qt + (size_t)NB * NN * CQ;

  float* out0 = (float*)d_out;
  float* out1 = out0 + (size_t)NB * NC * NN;
  bf16*  vf   = (bf16*)out1;  // scratch until copy_x runs

  // merged q (mt0, from x) + k (mt1, from skel) + v (mt2..9, from skel)
  proj_all<<<dim3(16, 10, NB), dim3(256), 0, stream>>>(
      x, skel, Wq, bq, Wk, bk, Wv, bv, qt, kt, vf);
  attn_flash<<<dim3(256), dim3(512), 0, stream>>>(qt, kt, vf, x, gamma, out0);
  copy_x<<<dim3(8192), dim3(256), 0, stream>>>(x, out1);
}

// Round 3
// 297.596 us; speedup vs baseline: 1.3391x; 1.1426x over previous
//
#include <hip/hip_runtime.h>
#include <hip/hip_bf16.h>

typedef __hip_bfloat16 bf16;
typedef __attribute__((ext_vector_type(8))) short short8;
typedef __attribute__((ext_vector_type(16))) float floatx16;

#define NB 4
#define NC 512
#define CQ 64
#define NN 4096
#define MFMA32 __builtin_amdgcn_mfma_f32_32x32x16_bf16

#define PQ 72   // qlds pitch (bf16): 144B rows, 16B aligned
#define PM 264  // plds pitch (bf16): 528B rows, 16B aligned
#define PA 40   // proj W-tile pitch
#define PB 40   // proj X-tile pitch

// vf layout: [b][m>>4][c][m&15] (m = spatial index, c = channel).
// PV fragment load (lane: c=col, 8 consecutive m at half*8) becomes ONE
// contiguous 1KB burst per instruction instead of a 32-row x 32B gather.
#define VSTEP (NC * 16)  // 8192 elements per 16-m group

// ---------------------------------------------------------------------------
// Merged q/k/v 1x1-conv GEMM: C[co][n] = W[co][c] * X[c][n] + bias.
// Tile 64co x 256n, BK=32. fp32 global -> bf16 LDS staging.
//   mt==0 : W=Wq, X=x,    write qt transposed [b][n][64]
//   mt==1 : W=Wk, X=skel, write kt transposed [b][n][64]
//   mt>=2 : W=Wv rows (mt-2)*64.., X=skel, write vf m-packed [b][m>>4][c][m&15]
// grid: (16 n-tiles, 10 m-tiles, NB), block 256.
// ---------------------------------------------------------------------------
__global__ __launch_bounds__(256) void proj_all(
    const float* __restrict__ x, const float* __restrict__ skel,
    const float* __restrict__ Wq, const float* __restrict__ bq,
    const float* __restrict__ Wk, const float* __restrict__ bk,
    const float* __restrict__ Wv, const float* __restrict__ bv,
    bf16* __restrict__ qt, bf16* __restrict__ ktO, bf16* __restrict__ vf) {
  __shared__ bf16 At[64 * PA];
  __shared__ bf16 Bt[256 * PB];
  int tid = threadIdx.x, lane = tid & 63, wave = tid >> 6;
  int col = lane & 31, half = lane >> 5;
  int nt = blockIdx.x, mt = blockIdx.y, b = blockIdx.z;
  int nbase = nt * 256;
  const float* Wp = (mt == 0) ? Wq
                  : (mt == 1) ? Wk
                              : Wv + (size_t)(mt - 2) * 64 * NC;
  const float* Xb = ((mt == 0) ? x : skel) + (size_t)b * NC * NN;

  floatx16 acc[2][2];
#pragma unroll
  for (int i = 0; i < 2; ++i)
#pragma unroll
    for (int j = 0; j < 2; ++j) acc[i][j] = (floatx16)(0.f);

  int wr = tid >> 2, wch = tid & 3;         // W staging: row, 8-wide k-chunk
  int xg = tid & 63, xc0 = (tid >> 6) * 8;  // X staging: n-group of 4, c-base

  for (int k0 = 0; k0 < NC; k0 += 32) {
    {  // stage W tile -> At[64][32]
      const float* wp = Wp + (size_t)wr * NC + k0 + wch * 8;
      float4 f0 = *(const float4*)(wp);
      float4 f1 = *(const float4*)(wp + 4);
      bf16 t8[8] = {__float2bfloat16(f0.x), __float2bfloat16(f0.y),
                    __float2bfloat16(f0.z), __float2bfloat16(f0.w),
                    __float2bfloat16(f1.x), __float2bfloat16(f1.y),
                    __float2bfloat16(f1.z), __float2bfloat16(f1.w)};
      *(uint4*)(At + wr * PA + wch * 8) = *(const uint4*)t8;
    }
    {  // stage X tile -> Bt[256][32] (transposed: [n][k])
      float xs[8][4];
#pragma unroll
      for (int cc = 0; cc < 8; ++cc) {
        float4 f = *(const float4*)(Xb + (size_t)(k0 + xc0 + cc) * NN + nbase + xg * 4);
        xs[cc][0] = f.x; xs[cc][1] = f.y; xs[cc][2] = f.z; xs[cc][3] = f.w;
      }
#pragma unroll
      for (int nn = 0; nn < 4; ++nn) {
        bf16 t8[8];
#pragma unroll
        for (int cc = 0; cc < 8; ++cc) t8[cc] = __float2bfloat16(xs[cc][nn]);
        *(uint4*)(Bt + (xg * 4 + nn) * PB + xc0) = *(const uint4*)t8;
      }
    }
    __syncthreads();
#pragma unroll
    for (int ks = 0; ks < 2; ++ks) {
      short8 a0 = *(const short8*)(At + col * PA + ks * 16 + half * 8);
      short8 a1 = *(const short8*)(At + (col + 32) * PA + ks * 16 + half * 8);
      short8 q0 = *(const short8*)(Bt + (wave * 64 + col) * PB + ks * 16 + half * 8);
      short8 q1 = *(const short8*)(Bt + (wave * 64 + 32 + col) * PB + ks * 16 + half * 8);
      acc[0][0] = MFMA32(a0, q0, acc[0][0], 0, 0, 0);
      acc[0][1] = MFMA32(a0, q1, acc[0][1], 0, 0, 0);
      acc[1][0] = MFMA32(a1, q0, acc[1][0], 0, 0, 0);
      acc[1][1] = MFMA32(a1, q1, acc[1][1], 0, 0, 0);
    }
    __syncthreads();
  }
  // epilogue: C/D layout col=lane&31 -> n, row=(r&3)+8*(r>>2)+4*half -> co
#pragma unroll
  for (int ms = 0; ms < 2; ++ms)
#pragma unroll
    for (int r = 0; r < 16; ++r) {
      int co = ms * 32 + (r & 3) + 8 * (r >> 2) + 4 * half;
      float bb = (mt == 0) ? bq[co] : (mt == 1) ? bk[co] : bv[(mt - 2) * 64 + co];
#pragma unroll
      for (int ns = 0; ns < 2; ++ns) {
        int n = nbase + wave * 64 + ns * 32 + col;
        float v = acc[ms][ns][r] + bb;
        if (mt == 0)
          qt[((size_t)b * NN + n) * CQ + co] = __float2bfloat16(v);
        else if (mt == 1)
          ktO[((size_t)b * NN + n) * CQ + co] = __float2bfloat16(v);
        else {
          int cog = (mt - 2) * 64 + co;
          vf[(size_t)b * NC * NN + (size_t)(n >> 4) * VSTEP + cog * 16 + (n & 15)] =
              __float2bfloat16(v);
        }
      }
    }
}

// ---------------------------------------------------------------------------
// Cooperative MFMA flash attention. Block = (batch, 64 queries), 8 waves
// (512 threads, 2 waves/SIMD). Per 256-m chunk: wave w computes S^T for its
// 32-m subtile (8 MFMA), softmax max/sum shared via LDS (2 barriers/chunk),
// P tile in LDS, then each wave does PV for its 64 channels (64 MFMA).
// XCD-aware grid: batch b pinned to XCD pair {2b,2b+1} so V[b] stays L2
// resident. V is m-packed [m>>4][c][m&15]: each PV fragment load is one
// contiguous 1KB burst (kills the 32-line gather = request-rate bottleneck).
// grid: 256 (1D), block 512.
// ---------------------------------------------------------------------------
__global__ __launch_bounds__(512, 2) void attn_flash(
    const bf16* __restrict__ qt, const bf16* __restrict__ kt,
    const bf16* __restrict__ vf, const float* __restrict__ x,
    const float* __restrict__ gamma, float* __restrict__ out0) {
  __shared__ bf16 qlds[64 * PQ];
  __shared__ bf16 plds[64 * PM];
  __shared__ float lred[8][2][32];
  __shared__ float sred[8][2][32];
  int tid = threadIdx.x, lane = tid & 63, wave = tid >> 6;
  int col = lane & 31, half = lane >> 5;
  // XCD-aware mapping (round-robin dispatch: XCD = bid % 8)
  int lid = blockIdx.x;
  int xcd = lid & 7;
  int b = xcd >> 1;
  int n0 = ((lid >> 3) * 2 + (xcd & 1)) * 64;
  const float L2E = 1.44269504f;

  // stage Q tile [64 n][64 cq]: 512 threads x one uint4
  {
    int r = tid >> 3, ch = tid & 7;
    *(uint4*)(qlds + r * PQ + ch * 8) =
        *(const uint4*)(qt + ((size_t)b * NN + n0 + r) * CQ + ch * 8);
  }
  __syncthreads();

  floatx16 acc[2][2];
#pragma unroll
  for (int t = 0; t < 2; ++t)
#pragma unroll
    for (int ns = 0; ns < 2; ++ns) acc[t][ns] = (floatx16)(0.f);
  float run_max[2] = {-3.0e38f, -3.0e38f}, run_sum[2] = {0.f, 0.f};

  const bf16* kb = kt + (size_t)b * NN * CQ;
  // per-lane V base: c = wave*64 + col (t adds t*32 channels = t*512 elems)
  const bf16* vbw = vf + (size_t)b * NC * NN + (size_t)(wave * 64 + col) * 16 + half * 8;

  for (int it = 0; it < 16; ++it) {
    int m0 = it * 256;
    int mw = m0 + wave * 32;
    // ---- S^T for this wave's 32-m subtile: D[m][n], n on lanes ----------
    floatx16 s[2];
#pragma unroll
    for (int ns = 0; ns < 2; ++ns) s[ns] = (floatx16)(0.f);
    const bf16* kp = kb + (size_t)(mw + col) * CQ + half * 8;
#pragma unroll
    for (int ks = 0; ks < 4; ++ks) {
      short8 a0 = *(const short8*)(kp + ks * 16);
      short8 q0 = *(const short8*)(qlds + col * PQ + ks * 16 + half * 8);
      short8 q1 = *(const short8*)(qlds + (32 + col) * PQ + ks * 16 + half * 8);
      s[0] = MFMA32(a0, q0, s[0], 0, 0, 0);
      s[1] = MFMA32(a0, q1, s[1], 0, 0, 0);
    }
    // ---- wave-local max over its 32 m, publish ---------------------------
#pragma unroll
    for (int ns = 0; ns < 2; ++ns) {
      float lm = s[ns][0];
#pragma unroll
      for (int r = 1; r < 16; ++r) lm = fmaxf(lm, s[ns][r]);
      lm = fmaxf(lm, __shfl_xor(lm, 32));
      if (half == 0) lred[wave][ns][col] = lm;
    }
    __syncthreads();  // A: lmax visible; also orders prev-iter PV before P-write
    float nm[2], alpha[2];
#pragma unroll
    for (int ns = 0; ns < 2; ++ns) {
      float m8 = lred[0][ns][col];
#pragma unroll
      for (int w = 1; w < 8; ++w) m8 = fmaxf(m8, lred[w][ns][col]);
      nm[ns] = fmaxf(run_max[ns], m8);
      alpha[ns] = exp2f((run_max[ns] - nm[ns]) * L2E);
      run_max[ns] = nm[ns];
    }
    // ---- P = exp(S - nm), write LDS [n][m-chunk 256], partial sums -------
    float psum[2] = {0.f, 0.f};
#pragma unroll
    for (int ns = 0; ns < 2; ++ns) {
      float pv[16];
#pragma unroll
      for (int r = 0; r < 16; ++r) {
        pv[r] = exp2f((s[ns][r] - nm[ns]) * L2E);
        psum[ns] += pv[r];
      }
      bf16* pw = plds + (ns * 32 + col) * PM + wave * 32 + 4 * half;
#pragma unroll
      for (int rg = 0; rg < 4; ++rg) {  // m = .. + rg*8 + {0,1,2,3}
        bf16 t4[4] = {__float2bfloat16(pv[4 * rg]), __float2bfloat16(pv[4 * rg + 1]),
                      __float2bfloat16(pv[4 * rg + 2]), __float2bfloat16(pv[4 * rg + 3])};
        *(uint2*)(pw + rg * 8) = *(const uint2*)t4;
      }
    }
#pragma unroll
    for (int ns = 0; ns < 2; ++ns) {
      float ps = psum[ns] + __shfl_xor(psum[ns], 32);
      if (half == 0) sred[wave][ns][col] = ps;
    }
    if (__any((alpha[0] < 1.f) || (alpha[1] < 1.f))) {
#pragma unroll
      for (int t = 0; t < 2; ++t)
#pragma unroll
        for (int ns = 0; ns < 2; ++ns)
#pragma unroll
          for (int r = 0; r < 16; ++r) acc[t][ns][r] *= alpha[ns];
    }
    __syncthreads();  // B: P + psums visible
#pragma unroll
    for (int ns = 0; ns < 2; ++ns) {
      float ss = sred[0][ns][col];
#pragma unroll
      for (int w = 1; w < 8; ++w) ss += sred[w][ns][col];
      run_sum[ns] = run_sum[ns] * alpha[ns] + ss;
    }
    // ---- PV over full 256-m chunk: D[c][n] += V[c][m] P^T[m][n] ----------
    // V fragment load: one contiguous 1KB burst per instruction (m-packed).
    const bf16* vp = vbw + (size_t)(m0 >> 4) * VSTEP;
#pragma unroll 4
    for (int ki = 0; ki < 16; ++ki) {
      short8 p0 = *(const short8*)(plds + col * PM + ki * 16 + half * 8);
      short8 p1 = *(const short8*)(plds + (32 + col) * PM + ki * 16 + half * 8);
      const bf16* vk = vp + (size_t)ki * VSTEP;
#pragma unroll
      for (int t = 0; t < 2; ++t) {
        short8 av = *(const short8*)(vk + t * 512);
        acc[t][0] = MFMA32(av, p0, acc[t][0], 0, 0, 0);
        acc[t][1] = MFMA32(av, p1, acc[t][1], 0, 0, 0);
      }
    }
  }
  // ---- epilogue: out0 = gamma/denom * acc + x ----------------------------
  float g = gamma[0];
  float scl[2] = {g / run_sum[0], g / run_sum[1]};
#pragma unroll
  for (int t = 0; t < 2; ++t)
#pragma unroll
    for (int r = 0; r < 16; ++r) {
      int c = wave * 64 + t * 32 + (r & 3) + 8 * (r >> 2) + 4 * half;
      size_t rowb = (size_t)b * NC * NN + (size_t)c * NN + n0 + col;
#pragma unroll
      for (int ns = 0; ns < 2; ++ns) {
        size_t idx = rowb + ns * 32;
        out0[idx] = scl[ns] * acc[t][ns][r] + x[idx];
      }
    }
}

// ---------------------------------------------------------------------------
// out1 = x flattened (exact fp32 copy), 4 elements / thread.
// ---------------------------------------------------------------------------
__global__ __launch_bounds__(256) void copy_x(const float* __restrict__ x,
                                              float* __restrict__ out1) {
  size_t i = ((size_t)blockIdx.x * 256 + threadIdx.x) * 4;
  *reinterpret_cast<float4*>(out1 + i) =
      *reinterpret_cast<const float4*>(x + i);
}

extern "C" void kernel_launch(void* const* d_in, const int* in_sizes, int n_in,
                              void* d_out, int out_size, void* d_ws,
                              size_t ws_size, hipStream_t stream) {
  const float* x     = (const float*)d_in[0];
  // d_in[1] = style (unused by the reference)
  const float* skel  = (const float*)d_in[2];
  const float* Wq    = (const float*)d_in[3];
  const float* bq    = (const float*)d_in[4];
  const float* Wk    = (const float*)d_in[5];
  const float* bk    = (const float*)d_in[6];
  const float* Wv    = (const float*)d_in[7];
  const float* bv    = (const float*)d_in[8];
  const float* gamma = (const float*)d_in[9];

  // ws (4 MB): qt [B][N][64] bf16 + kt [B][N][64] bf16.
  // vf [B][N/16][C][16] bf16 (16.8 MB, m-packed) lives in the out1 half of
  // d_out; attn reads vf / writes out0 only; copy_x overwrites out1 after.
  bf16* qt = (bf16*)d_ws;
  bf16* kt = qt + (size_t)NB * NN * CQ;

  float* out0 = (float*)d_out;
  float* out1 = out0 + (size_t)NB * NC * NN;
  bf16*  vf   = (bf16*)out1;  // scratch until copy_x runs

  // merged q (mt0, from x) + k (mt1, from skel) + v (mt2..9, from skel)
  proj_all<<<dim3(16, 10, NB), dim3(256), 0, stream>>>(
      x, skel, Wq, bq, Wk, bk, Wv, bv, qt, kt, vf);
  attn_flash<<<dim3(256), dim3(512), 0, stream>>>(qt, kt, vf, x, gamma, out0);
  copy_x<<<dim3(8192), dim3(256), 0, stream>>>(x, out1);
}

// Round 4
// 278.093 us; speedup vs baseline: 1.4330x; 1.0701x over previous
//
#include <hip/hip_runtime.h>
#include <hip/hip_bf16.h>

typedef __hip_bfloat16 bf16;
typedef __attribute__((ext_vector_type(8))) short short8;
typedef __attribute__((ext_vector_type(16))) float floatx16;

#define NB 4
#define NC 512
#define CQ 64
#define NN 4096
#define MFMA32 __builtin_amdgcn_mfma_f32_32x32x16_bf16

#define PQ 72   // qlds pitch (bf16): 144B rows, 16B aligned
#define PM 264  // plds pitch (bf16): 528B rows, 16B aligned
#define PA 40   // proj W-tile pitch
#define PB 40   // proj X-tile pitch

// vf layout: [b][m>>4][c][m&15] (m = spatial index, c = channel).
// PV fragment load (lane: c=col, 8 consecutive m at half*8) is ONE
// contiguous 1KB burst per instruction instead of a 32-row x 32B gather.
#define VSTEP (NC * 16)  // 8192 elements per 16-m group

// ---------------------------------------------------------------------------
// Merged q/k/v 1x1-conv GEMM: C[co][n] = W[co][c] * X[c][n] + bias.
// Tile 64co x 256n, BK=32. fp32 global -> bf16 LDS staging.
//   mt==0 : W=Wq, X=x,    write qt transposed [b][n][64]
//   mt==1 : W=Wk, X=skel, write kt transposed [b][n][64]
//   mt>=2 : W=Wv rows (mt-2)*64.., X=skel, write vf m-packed [b][m>>4][c][m&15]
// grid: (16 n-tiles, 10 m-tiles, NB), block 256.
// ---------------------------------------------------------------------------
__global__ __launch_bounds__(256) void proj_all(
    const float* __restrict__ x, const float* __restrict__ skel,
    const float* __restrict__ Wq, const float* __restrict__ bq,
    const float* __restrict__ Wk, const float* __restrict__ bk,
    const float* __restrict__ Wv, const float* __restrict__ bv,
    bf16* __restrict__ qt, bf16* __restrict__ ktO, bf16* __restrict__ vf) {
  __shared__ bf16 At[64 * PA];
  __shared__ bf16 Bt[256 * PB];
  int tid = threadIdx.x, lane = tid & 63, wave = tid >> 6;
  int col = lane & 31, half = lane >> 5;
  int nt = blockIdx.x, mt = blockIdx.y, b = blockIdx.z;
  int nbase = nt * 256;
  const float* Wp = (mt == 0) ? Wq
                  : (mt == 1) ? Wk
                              : Wv + (size_t)(mt - 2) * 64 * NC;
  const float* Xb = ((mt == 0) ? x : skel) + (size_t)b * NC * NN;

  floatx16 acc[2][2];
#pragma unroll
  for (int i = 0; i < 2; ++i)
#pragma unroll
    for (int j = 0; j < 2; ++j) acc[i][j] = (floatx16)(0.f);

  int wr = tid >> 2, wch = tid & 3;         // W staging: row, 8-wide k-chunk
  int xg = tid & 63, xc0 = (tid >> 6) * 8;  // X staging: n-group of 4, c-base

  for (int k0 = 0; k0 < NC; k0 += 32) {
    {  // stage W tile -> At[64][32]
      const float* wp = Wp + (size_t)wr * NC + k0 + wch * 8;
      float4 f0 = *(const float4*)(wp);
      float4 f1 = *(const float4*)(wp + 4);
      bf16 t8[8] = {__float2bfloat16(f0.x), __float2bfloat16(f0.y),
                    __float2bfloat16(f0.z), __float2bfloat16(f0.w),
                    __float2bfloat16(f1.x), __float2bfloat16(f1.y),
                    __float2bfloat16(f1.z), __float2bfloat16(f1.w)};
      *(uint4*)(At + wr * PA + wch * 8) = *(const uint4*)t8;
    }
    {  // stage X tile -> Bt[256][32] (transposed: [n][k])
      float xs[8][4];
#pragma unroll
      for (int cc = 0; cc < 8; ++cc) {
        float4 f = *(const float4*)(Xb + (size_t)(k0 + xc0 + cc) * NN + nbase + xg * 4);
        xs[cc][0] = f.x; xs[cc][1] = f.y; xs[cc][2] = f.z; xs[cc][3] = f.w;
      }
#pragma unroll
      for (int nn = 0; nn < 4; ++nn) {
        bf16 t8[8];
#pragma unroll
        for (int cc = 0; cc < 8; ++cc) t8[cc] = __float2bfloat16(xs[cc][nn]);
        *(uint4*)(Bt + (xg * 4 + nn) * PB + xc0) = *(const uint4*)t8;
      }
    }
    __syncthreads();
#pragma unroll
    for (int ks = 0; ks < 2; ++ks) {
      short8 a0 = *(const short8*)(At + col * PA + ks * 16 + half * 8);
      short8 a1 = *(const short8*)(At + (col + 32) * PA + ks * 16 + half * 8);
      short8 q0 = *(const short8*)(Bt + (wave * 64 + col) * PB + ks * 16 + half * 8);
      short8 q1 = *(const short8*)(Bt + (wave * 64 + 32 + col) * PB + ks * 16 + half * 8);
      acc[0][0] = MFMA32(a0, q0, acc[0][0], 0, 0, 0);
      acc[0][1] = MFMA32(a0, q1, acc[0][1], 0, 0, 0);
      acc[1][0] = MFMA32(a1, q0, acc[1][0], 0, 0, 0);
      acc[1][1] = MFMA32(a1, q1, acc[1][1], 0, 0, 0);
    }
    __syncthreads();
  }
  // epilogue: C/D layout col=lane&31 -> n, row=(r&3)+8*(r>>2)+4*half -> co
#pragma unroll
  for (int ms = 0; ms < 2; ++ms)
#pragma unroll
    for (int r = 0; r < 16; ++r) {
      int co = ms * 32 + (r & 3) + 8 * (r >> 2) + 4 * half;
      float bb = (mt == 0) ? bq[co] : (mt == 1) ? bk[co] : bv[(mt - 2) * 64 + co];
#pragma unroll
      for (int ns = 0; ns < 2; ++ns) {
        int n = nbase + wave * 64 + ns * 32 + col;
        float v = acc[ms][ns][r] + bb;
        if (mt == 0)
          qt[((size_t)b * NN + n) * CQ + co] = __float2bfloat16(v);
        else if (mt == 1)
          ktO[((size_t)b * NN + n) * CQ + co] = __float2bfloat16(v);
        else {
          int cog = (mt - 2) * 64 + co;
          vf[(size_t)b * NC * NN + (size_t)(n >> 4) * VSTEP + cog * 16 + (n & 15)] =
              __float2bfloat16(v);
        }
      }
    }
}

// ---------------------------------------------------------------------------
// Cooperative MFMA flash attention, channel-split. Block = (batch, 64
// queries, 256-channel half), 8 waves (512 threads). TWO blocks per CU (two
// independent barrier domains per SIMD -> 4 waves/SIMD whose stalls
// interleave). Each block computes full S^T/softmax for its 64 queries
// (duplicated across the channel pair — cheap) but PV only for its 256
// channels (wave owns 32 channels). V m-packed [m>>4][c][m&15] -> PV loads
// are contiguous 1KB bursts. XCD-aware: batch b pinned to XCD pair; the two
// channel-halves of one (b,n0) tile land on the same XCD (share K/Q in L2).
// grid: 512 (1D), block 512.
// ---------------------------------------------------------------------------
__global__ __launch_bounds__(512, 4) void attn_flash(
    const bf16* __restrict__ qt, const bf16* __restrict__ kt,
    const bf16* __restrict__ vf, const float* __restrict__ x,
    const float* __restrict__ gamma, float* __restrict__ out0) {
  __shared__ bf16 qlds[64 * PQ];
  __shared__ bf16 plds[64 * PM];
  __shared__ float lred[8][2][32];
  __shared__ float sred[8][2][32];
  int tid = threadIdx.x, lane = tid & 63, wave = tid >> 6;
  int col = lane & 31, half = lane >> 5;
  // XCD-aware mapping (round-robin dispatch: XCD = bid % 8)
  int lid = blockIdx.x;
  int xcd = lid & 7;
  int b = xcd >> 1;
  int hid = lid >> 3;        // 0..63 within XCD
  int ch = hid & 1;          // channel half (0: c 0..255, 1: c 256..511)
  int n0 = (((hid >> 1) * 2) + (xcd & 1)) * 64;
  const float L2E = 1.44269504f;

  // stage Q tile [64 n][64 cq]: 512 threads x one uint4
  {
    int r = tid >> 3, chq = tid & 7;
    *(uint4*)(qlds + r * PQ + chq * 8) =
        *(const uint4*)(qt + ((size_t)b * NN + n0 + r) * CQ + chq * 8);
  }
  __syncthreads();

  floatx16 acc[2];
#pragma unroll
  for (int ns = 0; ns < 2; ++ns) acc[ns] = (floatx16)(0.f);
  float run_max[2] = {-3.0e38f, -3.0e38f}, run_sum[2] = {0.f, 0.f};

  const bf16* kb = kt + (size_t)b * NN * CQ;
  // per-lane V base: c = ch*256 + wave*32 + col
  const bf16* vbw = vf + (size_t)b * NC * NN +
                    (size_t)(ch * 256 + wave * 32 + col) * 16 + half * 8;

  for (int it = 0; it < 16; ++it) {
    int m0 = it * 256;
    int mw = m0 + wave * 32;
    // ---- S^T for this wave's 32-m subtile: D[m][n], n on lanes ----------
    floatx16 s[2];
#pragma unroll
    for (int ns = 0; ns < 2; ++ns) s[ns] = (floatx16)(0.f);
    const bf16* kp = kb + (size_t)(mw + col) * CQ + half * 8;
#pragma unroll
    for (int ks = 0; ks < 4; ++ks) {
      short8 a0 = *(const short8*)(kp + ks * 16);
      short8 q0 = *(const short8*)(qlds + col * PQ + ks * 16 + half * 8);
      short8 q1 = *(const short8*)(qlds + (32 + col) * PQ + ks * 16 + half * 8);
      s[0] = MFMA32(a0, q0, s[0], 0, 0, 0);
      s[1] = MFMA32(a0, q1, s[1], 0, 0, 0);
    }
    // ---- wave-local max over its 32 m, publish ---------------------------
#pragma unroll
    for (int ns = 0; ns < 2; ++ns) {
      float lm = s[ns][0];
#pragma unroll
      for (int r = 1; r < 16; ++r) lm = fmaxf(lm, s[ns][r]);
      lm = fmaxf(lm, __shfl_xor(lm, 32));
      if (half == 0) lred[wave][ns][col] = lm;
    }
    __syncthreads();  // A: lmax visible; also orders prev-iter PV before P-write
    float nm[2], alpha[2];
#pragma unroll
    for (int ns = 0; ns < 2; ++ns) {
      float m8 = lred[0][ns][col];
#pragma unroll
      for (int w = 1; w < 8; ++w) m8 = fmaxf(m8, lred[w][ns][col]);
      nm[ns] = fmaxf(run_max[ns], m8);
      alpha[ns] = exp2f((run_max[ns] - nm[ns]) * L2E);
      run_max[ns] = nm[ns];
    }
    // ---- P = exp(S - nm), write LDS [n][m-chunk 256], partial sums -------
    float psum[2] = {0.f, 0.f};
#pragma unroll
    for (int ns = 0; ns < 2; ++ns) {
      float pv[16];
#pragma unroll
      for (int r = 0; r < 16; ++r) {
        pv[r] = exp2f((s[ns][r] - nm[ns]) * L2E);
        psum[ns] += pv[r];
      }
      bf16* pw = plds + (ns * 32 + col) * PM + wave * 32 + 4 * half;
#pragma unroll
      for (int rg = 0; rg < 4; ++rg) {  // m = .. + rg*8 + {0,1,2,3}
        bf16 t4[4] = {__float2bfloat16(pv[4 * rg]), __float2bfloat16(pv[4 * rg + 1]),
                      __float2bfloat16(pv[4 * rg + 2]), __float2bfloat16(pv[4 * rg + 3])};
        *(uint2*)(pw + rg * 8) = *(const uint2*)t4;
      }
    }
#pragma unroll
    for (int ns = 0; ns < 2; ++ns) {
      float ps = psum[ns] + __shfl_xor(psum[ns], 32);
      if (half == 0) sred[wave][ns][col] = ps;
    }
    if (__any((alpha[0] < 1.f) || (alpha[1] < 1.f))) {
#pragma unroll
      for (int ns = 0; ns < 2; ++ns)
#pragma unroll
        for (int r = 0; r < 16; ++r) acc[ns][r] *= alpha[ns];
    }
    __syncthreads();  // B: P + psums visible
#pragma unroll
    for (int ns = 0; ns < 2; ++ns) {
      float ss = sred[0][ns][col];
#pragma unroll
      for (int w = 1; w < 8; ++w) ss += sred[w][ns][col];
      run_sum[ns] = run_sum[ns] * alpha[ns] + ss;
    }
    // ---- PV over full 256-m chunk: D[c][n] += V[c][m] P^T[m][n] ----------
    // V fragment load: one contiguous 1KB burst per instruction (m-packed).
    const bf16* vp = vbw + (size_t)(m0 >> 4) * VSTEP;
#pragma unroll 4
    for (int ki = 0; ki < 16; ++ki) {
      short8 p0 = *(const short8*)(plds + col * PM + ki * 16 + half * 8);
      short8 p1 = *(const short8*)(plds + (32 + col) * PM + ki * 16 + half * 8);
      short8 av = *(const short8*)(vp + (size_t)ki * VSTEP);
      acc[0] = MFMA32(av, p0, acc[0], 0, 0, 0);
      acc[1] = MFMA32(av, p1, acc[1], 0, 0, 0);
    }
  }
  // ---- epilogue: out0 = gamma/denom * acc + x ----------------------------
  float g = gamma[0];
  float scl[2] = {g / run_sum[0], g / run_sum[1]};
#pragma unroll
  for (int r = 0; r < 16; ++r) {
    int c = ch * 256 + wave * 32 + (r & 3) + 8 * (r >> 2) + 4 * half;
    size_t rowb = (size_t)b * NC * NN + (size_t)c * NN + n0 + col;
#pragma unroll
    for (int ns = 0; ns < 2; ++ns) {
      size_t idx = rowb + ns * 32;
      out0[idx] = scl[ns] * acc[ns][r] + x[idx];
    }
  }
}

// ---------------------------------------------------------------------------
// out1 = x flattened (exact fp32 copy), 4 elements / thread.
// ---------------------------------------------------------------------------
__global__ __launch_bounds__(256) void copy_x(const float* __restrict__ x,
                                              float* __restrict__ out1) {
  size_t i = ((size_t)blockIdx.x * 256 + threadIdx.x) * 4;
  *reinterpret_cast<float4*>(out1 + i) =
      *reinterpret_cast<const float4*>(x + i);
}

extern "C" void kernel_launch(void* const* d_in, const int* in_sizes, int n_in,
                              void* d_out, int out_size, void* d_ws,
                              size_t ws_size, hipStream_t stream) {
  const float* x     = (const float*)d_in[0];
  // d_in[1] = style (unused by the reference)
  const float* skel  = (const float*)d_in[2];
  const float* Wq    = (const float*)d_in[3];
  const float* bq    = (const float*)d_in[4];
  const float* Wk    = (const float*)d_in[5];
  const float* bk    = (const float*)d_in[6];
  const float* Wv    = (const float*)d_in[7];
  const float* bv    = (const float*)d_in[8];
  const float* gamma = (const float*)d_in[9];

  // ws (4 MB): qt [B][N][64] bf16 + kt [B][N][64] bf16.
  // vf [B][N/16][C][16] bf16 (16.8 MB, m-packed) lives in the out1 half of
  // d_out; attn reads vf / writes out0 only; copy_x overwrites out1 after.
  bf16* qt = (bf16*)d_ws;
  bf16* kt = qt + (size_t)NB * NN * CQ;

  float* out0 = (float*)d_out;
  float* out1 = out0 + (size_t)NB * NC * NN;
  bf16*  vf   = (bf16*)out1;  // scratch until copy_x runs

  // merged q (mt0, from x) + k (mt1, from skel) + v (mt2..9, from skel)
  proj_all<<<dim3(16, 10, NB), dim3(256), 0, stream>>>(
      x, skel, Wq, bq, Wk, bk, Wv, bv, qt, kt, vf);
  attn_flash<<<dim3(512), dim3(512), 0, stream>>>(qt, kt, vf, x, gamma, out0);
  copy_x<<<dim3(8192), dim3(256), 0, stream>>>(x, out1);
}